// Round 6
// baseline (332.121 us; speedup 1.0000x reference)
//
#include <hip/hip_runtime.h>
#include <hip/hip_bf16.h>
#include <math.h>

typedef __attribute__((ext_vector_type(4))) float  f32x4;
typedef __attribute__((ext_vector_type(8))) short  short8;
typedef __attribute__((ext_vector_type(4))) short  short4_t;

#define DTC   0.1f
#define EPSF  1e-6f
// lower-triangle (i>=j) of 64x64: 2080 pairs, padded to 2176 = 17*128 packed cols
#define NPACK 2176
#define NTRI  2080
#define NB    8      // batches per g2fin block

static __device__ __forceinline__ unsigned short f2bf(float f) {
    union { float f; unsigned int u; } v; v.f = f;
    unsigned int u = v.u;
    return (unsigned short)((u + 0x7FFFu + ((u >> 16) & 1u)) >> 16);  // RNE
}
static __device__ __forceinline__ unsigned short f2bf_hw(float f) {
    __hip_bfloat16 b = __float2bfloat16(f);
    union { __hip_bfloat16 b; unsigned short u; } v; v.b = b;
    return v.u;
}
static __device__ __forceinline__ float bf2f(unsigned short b) {
    union { unsigned int u; float f; } v; v.u = ((unsigned int)b) << 16;
    return v.f;
}
// packed index p (0..2079) -> (i,j), i>=j. Row r pairs diag r (len 64-r) with
// diag 63-r (len r+1): 32 rows * 65 = 2080.
static __device__ __forceinline__ void tri_unpack(int p, int& i, int& j) {
    int r = p / 65, c = p - r * 65;
    if (c < 64 - r) { j = c;            i = c + r;       }
    else            { j = c - 64 + r;   i = j + 63 - r;  }
}

static __device__ __forceinline__ void gload_lds16(const void* gptr, void* ldsptr) {
    __builtin_amdgcn_global_load_lds(
        (const __attribute__((address_space(1))) unsigned int*)gptr,
        (__attribute__((address_space(3))) unsigned int*)ldsptr, 16, 0, 0);
}

// ---------------- pack: W1 -> bf16 ; W2/b2 -> lower-tri-packed bf16/f32 rows
__global__ __launch_bounds__(256) void pack_k(const float* __restrict__ W1,
                                              const float* __restrict__ W2,
                                              const float* __restrict__ b2,
                                              unsigned short* __restrict__ w1b,
                                              unsigned short* __restrict__ w2p,
                                              float* __restrict__ b2p) {
    const int bid = blockIdx.x, t = threadIdx.x;
    if (bid < 1024) {                       // W1: 1,048,576 f32 = 262,144 f32x4
        int idx = bid * 256 + t;
        f32x4 v = ((const f32x4*)W1)[idx];
        short4_t o;
        o[0] = (short)f2bf(v[0]); o[1] = (short)f2bf(v[1]);
        o[2] = (short)f2bf(v[2]); o[3] = (short)f2bf(v[3]);
        ((short4_t*)w1b)[idx] = o;
    } else {                                // one block per packed row p
        int p = bid - 1024;                 // 0..2175
        if (p < NTRI) {
            int i, j; tri_unpack(p, i, j);
            w2p[p * 256 + t] = f2bf(W2[(i * 64 + j) * 256L + t]);
            if (t == 0) b2p[p] = b2[i * 64 + j];
        } else {
            w2p[p * 256 + t] = 0;
            if (t == 0) b2p[p] = 0.f;
        }
    }
}

// --------- GEMM1: BM=64, BN=256(full), split-K=8; f32 A cast in staging; bf16 partials
// P[kz][8192,256] = metric[8192, kz*512:+512] @ W1bf[256, same]^T   (round-4 proven)
__global__ __launch_bounds__(256, 2) void gemm1_k(const float* __restrict__ A,
                                                  const unsigned short* __restrict__ B,
                                                  unsigned short* __restrict__ P) {
    __shared__ unsigned short As[64 * 64];    // 8 KB
    __shared__ unsigned short Bs[256 * 64];   // 32 KB
    const int tid  = threadIdx.x;
    const int lane = tid & 63;
    const int w    = tid >> 6;
    const int wm   = w >> 1, wn = w & 1;      // wave tile: 32 rows x 128 cols
    const long bm  = (long)blockIdx.x * 64;
    const int  kz  = blockIdx.y;

    f32x4 acc[2][8];
#pragma unroll
    for (int m = 0; m < 2; m++)
#pragma unroll
        for (int n = 0; n < 8; n++) acc[m][n] = (f32x4){0.f, 0.f, 0.f, 0.f};

    const int rB = tid >> 3;         // 0..31
    const int cB = (tid & 7) * 8;    // bf16 col

    for (int kk = kz * 512; kk < kz * 512 + 512; kk += 64) {
#pragma unroll
        for (int i = 0; i < 8; i++)
            gload_lds16(B + (i * 32 + rB) * 4096L + kk + cB,
                        (char*)Bs + i * 4096 + tid * 16);
#pragma unroll
        for (int i = 0; i < 2; i++) {
            const int row = i * 32 + rB;
            const float* src = A + (bm + row) * 4096L + kk + cB;
            f32x4 a0 = ((const f32x4*)src)[0];
            f32x4 a1 = ((const f32x4*)src)[1];
            short8 ob;
#pragma unroll
            for (int e = 0; e < 4; e++) ob[e]     = (short)f2bf_hw(a0[e]);
#pragma unroll
            for (int e = 0; e < 4; e++) ob[4 + e] = (short)f2bf_hw(a1[e]);
            *(short8*)&As[row * 64 + cB] = ob;
        }
        __syncthreads();

#pragma unroll
        for (int kq = 0; kq < 2; kq++) {
            short8 af0 = *(const short8*)&As[(wm * 32 + 0 * 16 + (lane & 15)) * 64 +
                                             kq * 32 + (lane >> 4) * 8];
            short8 af1 = *(const short8*)&As[(wm * 32 + 1 * 16 + (lane & 15)) * 64 +
                                             kq * 32 + (lane >> 4) * 8];
#pragma unroll
            for (int n = 0; n < 8; n++) {
                short8 bfn = *(const short8*)&Bs[(wn * 128 + n * 16 + (lane & 15)) * 64 +
                                                 kq * 32 + (lane >> 4) * 8];
                acc[0][n] = __builtin_amdgcn_mfma_f32_16x16x32_bf16(af0, bfn, acc[0][n], 0, 0, 0);
                acc[1][n] = __builtin_amdgcn_mfma_f32_16x16x32_bf16(af1, bfn, acc[1][n], 0, 0, 0);
            }
        }
        __syncthreads();
    }

    unsigned short* Pk = P + (long)kz * (8192L * 256);
#pragma unroll
    for (int n = 0; n < 8; n++) {
        long col = wn * 128 + n * 16 + (lane & 15);
#pragma unroll
        for (int m = 0; m < 2; m++)
#pragma unroll
            for (int r = 0; r < 4; r++) {
                long row = bm + wm * 32 + m * 16 + (lane >> 4) * 4 + r;
                Pk[row * 256 + col] = f2bf(acc[m][n][r]);
            }
    }
}

// --------------------------------- reduce 8 bf16 partials + b1 + tanh -> h (bf16)
__global__ __launch_bounds__(256) void reduce_h_k(const unsigned short* __restrict__ P,
                                                  const float* __restrict__ b1,
                                                  unsigned short* __restrict__ h) {
    const int idx = blockIdx.x * 256 + threadIdx.x;   // 262,144 short8 groups
    float s[8];
#pragma unroll
    for (int e = 0; e < 8; e++) s[e] = 0.f;
#pragma unroll
    for (int kz = 0; kz < 8; kz++) {
        short8 v = ((const short8*)(P + (long)kz * 2097152))[idx];
#pragma unroll
        for (int e = 0; e < 8; e++) s[e] += bf2f((unsigned short)v[e]);
    }
    const int cb = (idx & 31) * 8;
    f32x4 bv0 = *(const f32x4*)(b1 + cb);
    f32x4 bv1 = *(const f32x4*)(b1 + cb + 4);
    short8 o;
#pragma unroll
    for (int e = 0; e < 4; e++) o[e]     = (short)f2bf(tanhf(s[e] + bv0[e]));
#pragma unroll
    for (int e = 0; e < 4; e++) o[4 + e] = (short)f2bf(tanhf(s[4 + e] + bv1[e]));
    ((short8*)h)[idx] = o;
}

// ---- g2fin: per block, NB=8 batches.
// Phase 1: mlp rows (8 x 2176) = h[8,256] @ W2p^T + b2p  -> LDS (bf16), B from L2.
// Phase 2: per batch: scatter mlp -> s_f, fold -2*ricci, norms -> adt, out write.
__global__ __launch_bounds__(256, 3) void g2fin_k(const float* __restrict__ metric,
                                                  const float* __restrict__ ricci,
                                                  const unsigned short* __restrict__ h,
                                                  const unsigned short* __restrict__ w2p,
                                                  const float* __restrict__ b2p,
                                                  float* __restrict__ out) {
    __shared__ unsigned short s_mlp[NB * NPACK];   // 34,816 B
    __shared__ float s_f[64 * 65];                 // 16,640 B
    __shared__ float red[8];
    __shared__ float s_adt;

    const int tid  = threadIdx.x;
    const int lane = tid & 63;
    const int w    = tid >> 6;          // 4 waves
    const long b0  = (long)blockIdx.x * NB;

    // ---------- phase 1: GEMM into LDS ----------
    // A-fragments (8 k-steps): row = lane&15 (valid < 8), k = kq*32 + (lane>>4)*8
    short8 afr[8];
    {
        const int r = lane & 15;
#pragma unroll
        for (int kq = 0; kq < 8; kq++) {
            short8 v = (short8){0, 0, 0, 0, 0, 0, 0, 0};
            if (r < 8)
                v = *(const short8*)(h + (b0 + r) * 256 + kq * 32 + (lane >> 4) * 8);
            afr[kq] = v;
        }
    }
    // 136 col-tiles of 16, wave-strided
#pragma unroll 2
    for (int ct = w; ct < 136; ct += 4) {
        const int col = ct * 16 + (lane & 15);
        const unsigned short* bp = w2p + (long)col * 256 + (lane >> 4) * 8;
        f32x4 acc = (f32x4){0.f, 0.f, 0.f, 0.f};
#pragma unroll
        for (int kq = 0; kq < 8; kq++) {
            short8 bfr = *(const short8*)(bp + kq * 32);
            acc = __builtin_amdgcn_mfma_f32_16x16x32_bf16(afr[kq], bfr, acc, 0, 0, 0);
        }
        const float bv = b2p[col];
        const int row0 = (lane >> 4) * 4;      // rows row0..row0+3; keep rows < 8
        if (row0 < 8) {
#pragma unroll
            for (int r = 0; r < 4; r++)
                s_mlp[(row0 + r) * NPACK + col] = f2bf(acc[r] + bv);
        }
    }
    __syncthreads();

    // ---------- phase 2: per-batch finalize ----------
    for (int bb = 0; bb < NB; bb++) {
        const long mbase = (b0 + bb) * 4096;

        // scatter packed mlp into s_f
        for (int p = tid; p < NTRI; p += 256) {
            int i, j; tri_unpack(p, i, j);
            s_f[i * 65 + j] = bf2f(s_mlp[bb * NPACK + p]);
        }
        __syncthreads();

        const f32x4* met4 = (const f32x4*)(metric + mbase);
        const f32x4* ric4 = (const f32x4*)(ricci + mbase);
        f32x4 mm[4];
        float msq = 0.f, rsq = 0.f;
#pragma unroll
        for (int k = 0; k < 4; k++) {
            int v = k * 256 + tid;
            f32x4 r = ric4[v];
            f32x4 m = met4[v];
            mm[k] = m;
            msq += m[0]*m[0] + m[1]*m[1] + m[2]*m[2] + m[3]*m[3];
            rsq += r[0]*r[0] + r[1]*r[1] + r[2]*r[2] + r[3]*r[3];
            int e0 = v * 4;
            int i = e0 >> 6, j0 = e0 & 63;
#pragma unroll
            for (int e = 0; e < 4; e++) {
                int j = j0 + e;
                if (j <= i) s_f[i * 65 + j] -= 2.f * r[e];
            }
        }
#pragma unroll
        for (int off = 32; off > 0; off >>= 1) {
            msq += __shfl_down(msq, off);
            rsq += __shfl_down(rsq, off);
        }
        if ((tid & 63) == 0) { red[w] = msq; red[4 + w] = rsq; }
        __syncthreads();
        if (tid == 0) {
            float tm = red[0] + red[1] + red[2] + red[3];
            float tr = red[4] + red[5] + red[6] + red[7];
            s_adt = DTC * fminf(1.0f, 0.1f * sqrtf(tm) / (sqrtf(tr) + EPSF));
        }
        __syncthreads();

        const float adt = s_adt;
        f32x4* out4 = (f32x4*)(out + mbase);
#pragma unroll
        for (int k = 0; k < 4; k++) {
            int v = k * 256 + tid;
            int e0 = v * 4;
            int i = e0 >> 6, j0 = e0 & 63;
            f32x4 o;
#pragma unroll
            for (int e = 0; e < 4; e++) {
                int j = j0 + e;
                int mx = i > j ? i : j;
                int mn = i > j ? j : i;
                o[e] = mm[k][e] + adt * s_f[mx * 65 + mn];
            }
            out4[v] = o;
        }
        __syncthreads();   // s_f reused next batch
    }
}

// ---------------------------------------------------------------------- launcher
extern "C" void kernel_launch(void* const* d_in, const int* in_sizes, int n_in,
                              void* d_out, int out_size, void* d_ws, size_t ws_size,
                              hipStream_t stream) {
    const float* metric = (const float*)d_in[0];  // [8192,64,64]
    const float* ricci  = (const float*)d_in[1];  // [8192,64,64]
    const float* W1     = (const float*)d_in[2];  // [256,4096]
    const float* b1     = (const float*)d_in[3];  // [256]
    const float* W2     = (const float*)d_in[4];  // [4096,256]
    const float* b2     = (const float*)d_in[5];  // [4096]
    float* out = (float*)d_out;

    const int B = 8192;

    char* ws = (char*)d_ws;
    unsigned short* w1b  = (unsigned short*)(ws);                // 2,097,152
    unsigned short* w2p  = (unsigned short*)(ws + 2097152);      // 2176*256*2 = 1,114,112
    float*          b2p  = (float*)(ws + 3211264);               // 2176*4     = 8,704
    unsigned short* hbf  = (unsigned short*)(ws + 3219968);      // 8192*256*2 = 4,194,304
    // split-K bf16 partials live in d_out (dead until g2fin): 8*8192*256*2 = 33.5 MB
    unsigned short* part = (unsigned short*)out;

    // pack/cast weights (W1 cast: blocks 0..1023; W2/b2 tri-pack: blocks 1024..3199)
    pack_k<<<dim3(1024 + NPACK), dim3(256), 0, stream>>>(W1, W2, b2, w1b, w2p, b2p);

    // GEMM1: BM=64 x BN=256(full) x split-K=8 -> bf16 partials in d_out
    gemm1_k<<<dim3(B / 64, 8), dim3(256), 0, stream>>>(metric, w1b, part);
    // h = tanh(sum partials + b1) -> bf16
    reduce_h_k<<<dim3(B * 256 / 8 / 256), dim3(256), 0, stream>>>(part, b1, hbf);
    // fused GEMM2 + finalize: out = metric + adt * sym_lower(-2*ricci + h@W2p^T+b2p)
    g2fin_k<<<dim3(B / NB), dim3(256), 0, stream>>>(metric, ricci, hbf, w2p, b2p, out);

    (void)in_sizes; (void)n_in; (void)out_size; (void)ws_size;
}

// Round 7
// 163.604 us; speedup vs baseline: 2.0300x; 2.0300x over previous
//
#include <hip/hip_runtime.h>
#include <hip/hip_bf16.h>
#include <math.h>

typedef __attribute__((ext_vector_type(4))) float  f32x4;
typedef __attribute__((ext_vector_type(8))) short  short8;
typedef __attribute__((ext_vector_type(4))) short  short4_t;

#define DTC   0.1f
#define EPSF  1e-6f
// lower-triangle (i>=j) of 64x64: 2080 pairs, padded to 2176 = 17*128 packed cols
#define NPACK 2176
#define NTRI  2080
#define SPLITK 4

static __device__ __forceinline__ unsigned short f2bf(float f) {
    union { float f; unsigned int u; } v; v.f = f;
    unsigned int u = v.u;
    return (unsigned short)((u + 0x7FFFu + ((u >> 16) & 1u)) >> 16);  // RNE
}
static __device__ __forceinline__ unsigned short f2bf_hw(float f) {
    __hip_bfloat16 b = __float2bfloat16(f);
    union { __hip_bfloat16 b; unsigned short u; } v; v.b = b;
    return v.u;
}
static __device__ __forceinline__ float bf2f(unsigned short b) {
    union { unsigned int u; float f; } v; v.u = ((unsigned int)b) << 16;
    return v.f;
}
// packed index p (0..2079) -> (i,j), i>=j. Row r pairs diag r (len 64-r) with
// diag 63-r (len r+1): 32 rows * 65 = 2080.
static __device__ __forceinline__ void tri_unpack(int p, int& i, int& j) {
    int r = p / 65, c = p - r * 65;
    if (c < 64 - r) { j = c;            i = c + r;       }
    else            { j = c - 64 + r;   i = j + 63 - r;  }
}

static __device__ __forceinline__ void gload_lds16(const void* gptr, void* ldsptr) {
    __builtin_amdgcn_global_load_lds(
        (const __attribute__((address_space(1))) unsigned int*)gptr,
        (__attribute__((address_space(3))) unsigned int*)ldsptr, 16, 0, 0);
}

// ---------------- pack: W1 -> bf16 ; W2/b2 -> lower-tri-packed bf16/f32 rows
__global__ __launch_bounds__(256) void pack_k(const float* __restrict__ W1,
                                              const float* __restrict__ W2,
                                              const float* __restrict__ b2,
                                              unsigned short* __restrict__ w1b,
                                              unsigned short* __restrict__ w2p,
                                              float* __restrict__ b2p) {
    const int bid = blockIdx.x, t = threadIdx.x;
    if (bid < 1024) {                       // W1: 1,048,576 f32 = 262,144 f32x4
        int idx = bid * 256 + t;
        f32x4 v = ((const f32x4*)W1)[idx];
        short4_t o;
        o[0] = (short)f2bf(v[0]); o[1] = (short)f2bf(v[1]);
        o[2] = (short)f2bf(v[2]); o[3] = (short)f2bf(v[3]);
        ((short4_t*)w1b)[idx] = o;
    } else {                                // one block per packed row p
        int p = bid - 1024;                 // 0..2175
        if (p < NTRI) {
            int i, j; tri_unpack(p, i, j);
            w2p[p * 256 + t] = f2bf(W2[(i * 64 + j) * 256L + t]);
            if (t == 0) b2p[p] = b2[i * 64 + j];
        } else {
            w2p[p * 256 + t] = 0;
            if (t == 0) b2p[p] = 0.f;
        }
    }
}

// --------- GEMM1: BM=64, BN=256(full), split-K=4; f32 A cast in staging; bf16 partials
// P[kz][8192,256] = metric[8192, kz*1024:+1024] @ W1bf[256, same]^T
__global__ __launch_bounds__(256, 2) void gemm1_k(const float* __restrict__ A,
                                                  const unsigned short* __restrict__ B,
                                                  unsigned short* __restrict__ P) {
    __shared__ unsigned short As[64 * 64];    // 8 KB
    __shared__ unsigned short Bs[256 * 64];   // 32 KB
    const int tid  = threadIdx.x;
    const int lane = tid & 63;
    const int w    = tid >> 6;
    const int wm   = w >> 1, wn = w & 1;      // wave tile: 32 rows x 128 cols
    const long bm  = (long)blockIdx.x * 64;
    const int  kz  = blockIdx.y;

    f32x4 acc[2][8];
#pragma unroll
    for (int m = 0; m < 2; m++)
#pragma unroll
        for (int n = 0; n < 8; n++) acc[m][n] = (f32x4){0.f, 0.f, 0.f, 0.f};

    const int rB = tid >> 3;         // 0..31
    const int cB = (tid & 7) * 8;    // bf16 col

    for (int kk = kz * 1024; kk < kz * 1024 + 1024; kk += 64) {
#pragma unroll
        for (int i = 0; i < 8; i++)
            gload_lds16(B + (i * 32 + rB) * 4096L + kk + cB,
                        (char*)Bs + i * 4096 + tid * 16);
#pragma unroll
        for (int i = 0; i < 2; i++) {
            const int row = i * 32 + rB;
            const float* src = A + (bm + row) * 4096L + kk + cB;
            f32x4 a0 = ((const f32x4*)src)[0];
            f32x4 a1 = ((const f32x4*)src)[1];
            short8 ob;
#pragma unroll
            for (int e = 0; e < 4; e++) ob[e]     = (short)f2bf_hw(a0[e]);
#pragma unroll
            for (int e = 0; e < 4; e++) ob[4 + e] = (short)f2bf_hw(a1[e]);
            *(short8*)&As[row * 64 + cB] = ob;
        }
        __syncthreads();

#pragma unroll
        for (int kq = 0; kq < 2; kq++) {
            short8 af0 = *(const short8*)&As[(wm * 32 + 0 * 16 + (lane & 15)) * 64 +
                                             kq * 32 + (lane >> 4) * 8];
            short8 af1 = *(const short8*)&As[(wm * 32 + 1 * 16 + (lane & 15)) * 64 +
                                             kq * 32 + (lane >> 4) * 8];
#pragma unroll
            for (int n = 0; n < 8; n++) {
                short8 bfn = *(const short8*)&Bs[(wn * 128 + n * 16 + (lane & 15)) * 64 +
                                                 kq * 32 + (lane >> 4) * 8];
                acc[0][n] = __builtin_amdgcn_mfma_f32_16x16x32_bf16(af0, bfn, acc[0][n], 0, 0, 0);
                acc[1][n] = __builtin_amdgcn_mfma_f32_16x16x32_bf16(af1, bfn, acc[1][n], 0, 0, 0);
            }
        }
        __syncthreads();
    }

    unsigned short* Pk = P + (long)kz * (8192L * 256);
#pragma unroll
    for (int n = 0; n < 8; n++) {
        long col = wn * 128 + n * 16 + (lane & 15);
#pragma unroll
        for (int m = 0; m < 2; m++)
#pragma unroll
            for (int r = 0; r < 4; r++) {
                long row = bm + wm * 32 + m * 16 + (lane >> 4) * 4 + r;
                Pk[row * 256 + col] = f2bf(acc[m][n][r]);
            }
    }
}

// --------------------------------- reduce 4 bf16 partials + b1 + tanh -> h (bf16)
__global__ __launch_bounds__(256) void reduce_h_k(const unsigned short* __restrict__ P,
                                                  const float* __restrict__ b1,
                                                  unsigned short* __restrict__ h) {
    const int idx = blockIdx.x * 256 + threadIdx.x;   // 262,144 short8 groups
    float s[8];
#pragma unroll
    for (int e = 0; e < 8; e++) s[e] = 0.f;
#pragma unroll
    for (int kz = 0; kz < SPLITK; kz++) {
        short8 v = ((const short8*)(P + (long)kz * 2097152))[idx];
#pragma unroll
        for (int e = 0; e < 8; e++) s[e] += bf2f((unsigned short)v[e]);
    }
    const int cb = (idx & 31) * 8;
    f32x4 bv0 = *(const f32x4*)(b1 + cb);
    f32x4 bv1 = *(const f32x4*)(b1 + cb + 4);
    short8 o;
#pragma unroll
    for (int e = 0; e < 4; e++) o[e]     = (short)f2bf(tanhf(s[e] + bv0[e]));
#pragma unroll
    for (int e = 0; e < 4; e++) o[4 + e] = (short)f2bf(tanhf(s[4 + e] + bv1[e]));
    ((short8*)h)[idx] = o;
}

// ------------------- GEMM2 packed: mlpP[8192,2176] = h @ W2p^T + b2p -> bf16
// BM=128, BN=128, BK=128 (2 k-steps)
__global__ __launch_bounds__(256, 2) void gemm2p_k(const unsigned short* __restrict__ A,
                                                   const unsigned short* __restrict__ B,
                                                   const float* __restrict__ bias,
                                                   unsigned short* __restrict__ C) {
    __shared__ unsigned short As[128 * 128];   // 32 KB
    __shared__ unsigned short Bs[128 * 128];   // 32 KB
    const int tid  = threadIdx.x;
    const int lane = tid & 63;
    const int w    = tid >> 6;
    const int wm   = w >> 1, wn = w & 1;
    const long bm  = (long)blockIdx.x * 128;
    const long bn  = (long)blockIdx.y * 128;   // < 2176

    f32x4 acc[4][4];
#pragma unroll
    for (int m = 0; m < 4; m++)
#pragma unroll
        for (int n = 0; n < 4; n++) acc[m][n] = (f32x4){0.f, 0.f, 0.f, 0.f};

    for (int kk = 0; kk < 256; kk += 128) {
        // stage 128x128 bf16 of A and B: 2048 units of 16B each, 8 units/thread
#pragma unroll
        for (int i = 0; i < 8; i++) {
            const int unit = i * 256 + tid;
            const int row = unit >> 4, cu = unit & 15;
            gload_lds16(A + (bm + row) * 256L + kk + cu * 8, (char*)As + unit * 16);
            gload_lds16(B + (bn + row) * 256L + kk + cu * 8, (char*)Bs + unit * 16);
        }
        __syncthreads();

#pragma unroll
        for (int kq = 0; kq < 4; kq++) {
            short8 af[4], bf[4];
#pragma unroll
            for (int m = 0; m < 4; m++)
                af[m] = *(const short8*)&As[(wm * 64 + m * 16 + (lane & 15)) * 128 +
                                            kq * 32 + (lane >> 4) * 8];
#pragma unroll
            for (int n = 0; n < 4; n++)
                bf[n] = *(const short8*)&Bs[(wn * 64 + n * 16 + (lane & 15)) * 128 +
                                            kq * 32 + (lane >> 4) * 8];
#pragma unroll
            for (int m = 0; m < 4; m++)
#pragma unroll
                for (int n = 0; n < 4; n++)
                    acc[m][n] = __builtin_amdgcn_mfma_f32_16x16x32_bf16(af[m], bf[n],
                                                                        acc[m][n], 0, 0, 0);
        }
        __syncthreads();
    }

#pragma unroll
    for (int n = 0; n < 4; n++) {
        long col = bn + wn * 64 + n * 16 + (lane & 15);
        float bv = bias[col];
#pragma unroll
        for (int m = 0; m < 4; m++)
#pragma unroll
            for (int r = 0; r < 4; r++) {
                long row = bm + wm * 64 + m * 16 + (lane >> 4) * 4 + r;
                C[row * NPACK + col] = f2bf(acc[m][n][r] + bv);
            }
    }
}

// ---- finalize: scatter packed mlp -> tri LDS; norms -> adt; out = metric + adt*F_sym
__global__ __launch_bounds__(256) void finalize3_k(const float* __restrict__ metric,
                                                   const float* __restrict__ ricci,
                                                   const unsigned short* __restrict__ mlpP,
                                                   float* __restrict__ out) {
    const int b = blockIdx.x;
    const int t = threadIdx.x;
    const long mbase = (long)b * 4096;
    const long pbase = (long)b * NPACK;
    __shared__ float s_f[64 * 65];  // lower-tri values live at [i*65 + j], j<=i
    __shared__ float red[8];
    __shared__ float s_adt;

    // phase 1: scatter packed mlp (bf16) into s_f
    const short8* mp8 = (const short8*)(mlpP + pbase);
    {
        short8 v = mp8[t];                       // p = t*8 .. t*8+7  (< 2048)
#pragma unroll
        for (int e = 0; e < 8; e++) {
            int p = t * 8 + e, i, j;
            tri_unpack(p, i, j);
            s_f[i * 65 + j] = bf2f((unsigned short)v[e]);
        }
        if (t < 4) {                             // p = 2048 .. 2079
            short8 v2 = mp8[256 + t];
#pragma unroll
            for (int e = 0; e < 8; e++) {
                int p = 2048 + t * 8 + e, i, j;
                tri_unpack(p, i, j);
                s_f[i * 65 + j] = bf2f((unsigned short)v2[e]);
            }
        }
    }
    __syncthreads();

    // phase 2: norms + fold -2*ricci into lower-tri slots (unique owner per slot)
    const f32x4* met4 = (const f32x4*)(metric + mbase);
    const f32x4* ric4 = (const f32x4*)(ricci + mbase);
    f32x4 mm[4];
    float msq = 0.f, rsq = 0.f;
#pragma unroll
    for (int k = 0; k < 4; k++) {
        int v = k * 256 + t;
        f32x4 r = ric4[v];
        f32x4 m = met4[v];
        mm[k] = m;
        msq += m[0]*m[0] + m[1]*m[1] + m[2]*m[2] + m[3]*m[3];
        rsq += r[0]*r[0] + r[1]*r[1] + r[2]*r[2] + r[3]*r[3];
        int e0 = v * 4;
        int i = e0 >> 6, j0 = e0 & 63;
#pragma unroll
        for (int e = 0; e < 4; e++) {
            int j = j0 + e;
            if (j <= i) s_f[i * 65 + j] -= 2.f * r[e];
        }
    }
#pragma unroll
    for (int off = 32; off > 0; off >>= 1) {
        msq += __shfl_down(msq, off);
        rsq += __shfl_down(rsq, off);
    }
    if ((t & 63) == 0) { red[t >> 6] = msq; red[4 + (t >> 6)] = rsq; }
    __syncthreads();
    if (t == 0) {
        float tm = red[0] + red[1] + red[2] + red[3];
        float tr = red[4] + red[5] + red[6] + red[7];
        s_adt = DTC * fminf(1.0f, 0.1f * sqrtf(tm) / (sqrtf(tr) + EPSF));
    }
    __syncthreads();

    // phase 3: out = metric + adt * F[max][min]
    const float adt = s_adt;
    f32x4* out4 = (f32x4*)(out + mbase);
#pragma unroll
    for (int k = 0; k < 4; k++) {
        int v = k * 256 + t;
        int e0 = v * 4;
        int i = e0 >> 6, j0 = e0 & 63;
        f32x4 o;
#pragma unroll
        for (int e = 0; e < 4; e++) {
            int j = j0 + e;
            int mx = i > j ? i : j;
            int mn = i > j ? j : i;
            o[e] = mm[k][e] + adt * s_f[mx * 65 + mn];
        }
        out4[v] = o;
    }
}

// ---------------------------------------------------------------------- launcher
extern "C" void kernel_launch(void* const* d_in, const int* in_sizes, int n_in,
                              void* d_out, int out_size, void* d_ws, size_t ws_size,
                              hipStream_t stream) {
    const float* metric = (const float*)d_in[0];  // [8192,64,64]
    const float* ricci  = (const float*)d_in[1];  // [8192,64,64]
    const float* W1     = (const float*)d_in[2];  // [256,4096]
    const float* b1     = (const float*)d_in[3];  // [256]
    const float* W2     = (const float*)d_in[4];  // [4096,256]
    const float* b2     = (const float*)d_in[5];  // [4096]
    float* out = (float*)d_out;

    const int B = 8192;

    char* ws = (char*)d_ws;
    unsigned short* mlpP = (unsigned short*)(ws);                // 8192*2176*2 = 35,651,584
    unsigned short* w1b  = (unsigned short*)(ws + 35651584);     // 2,097,152
    unsigned short* w2p  = (unsigned short*)(ws + 37748736);     // 2176*256*2 = 1,114,112
    float*          b2p  = (float*)(ws + 38862848);              // 2176*4     = 8,704
    unsigned short* hbf  = (unsigned short*)(ws + 38871552);     // 8192*256*2 = 4,194,304
    // split-K bf16 partials live in d_out (dead until finalize): 4*8192*256*2 = 16 MB
    unsigned short* part = (unsigned short*)out;

    // pack/cast weights (W1 cast: blocks 0..1023; W2/b2 tri-pack: blocks 1024..3199)
    pack_k<<<dim3(1024 + NPACK), dim3(256), 0, stream>>>(W1, W2, b2, w1b, w2p, b2p);

    // GEMM1: BM=64 x BN=256(full) x split-K=4 -> bf16 partials in d_out
    gemm1_k<<<dim3(B / 64, SPLITK), dim3(256), 0, stream>>>(metric, w1b, part);
    // h = tanh(sum partials + b1) -> bf16
    reduce_h_k<<<dim3(B * 256 / 8 / 256), dim3(256), 0, stream>>>(part, b1, hbf);
    // mlpP = h @ W2p^T + b2p -> bf16 packed lower-tri columns (BK=128)
    gemm2p_k<<<dim3(B / 128, NPACK / 128), dim3(256), 0, stream>>>(hbf, w2p, b2p, mlpP);
    // out = metric + adt * sym_lower(-2*ricci + mlp)
    finalize3_k<<<dim3(B), dim3(256), 0, stream>>>(metric, ricci, mlpP, out);

    (void)in_sizes; (void)n_in; (void)out_size; (void)ws_size;
}

// Round 8
// 139.577 us; speedup vs baseline: 2.3795x; 1.1721x over previous
//
#include <hip/hip_runtime.h>
#include <hip/hip_bf16.h>
#include <math.h>

typedef __attribute__((ext_vector_type(4))) float  f32x4;
typedef __attribute__((ext_vector_type(8))) short  short8;
typedef __attribute__((ext_vector_type(4))) short  short4_t;

#define DTC   0.1f
#define EPSF  1e-6f
// lower-triangle (i>=j) of 64x64: 2080 pairs, padded to 2176 = 17*128 packed cols
#define NPACK 2176
#define NTRI  2080
#define SPLITK 8

static __device__ __forceinline__ unsigned short f2bf(float f) {
    union { float f; unsigned int u; } v; v.f = f;
    unsigned int u = v.u;
    return (unsigned short)((u + 0x7FFFu + ((u >> 16) & 1u)) >> 16);  // RNE
}
static __device__ __forceinline__ unsigned short f2bf_hw(float f) {
    __hip_bfloat16 b = __float2bfloat16(f);
    union { __hip_bfloat16 b; unsigned short u; } v; v.b = b;
    return v.u;
}
static __device__ __forceinline__ float bf2f(unsigned short b) {
    union { unsigned int u; float f; } v; v.u = ((unsigned int)b) << 16;
    return v.f;
}
// packed index p (0..2079) -> (i,j), i>=j. Row r pairs diag r (len 64-r) with
// diag 63-r (len r+1): 32 rows * 65 = 2080.
static __device__ __forceinline__ void tri_unpack(int p, int& i, int& j) {
    int r = p / 65, c = p - r * 65;
    if (c < 64 - r) { j = c;            i = c + r;       }
    else            { j = c - 64 + r;   i = j + 63 - r;  }
}

static __device__ __forceinline__ void gload_lds16(const void* gptr, void* ldsptr) {
    __builtin_amdgcn_global_load_lds(
        (const __attribute__((address_space(1))) unsigned int*)gptr,
        (__attribute__((address_space(3))) unsigned int*)ldsptr, 16, 0, 0);
}

// ---------------- pack: W1 -> bf16 ; W2/b2 -> lower-tri-packed bf16/f32 rows
__global__ __launch_bounds__(256) void pack_k(const float* __restrict__ W1,
                                              const float* __restrict__ W2,
                                              const float* __restrict__ b2,
                                              unsigned short* __restrict__ w1b,
                                              unsigned short* __restrict__ w2p,
                                              float* __restrict__ b2p) {
    const int bid = blockIdx.x, t = threadIdx.x;
    if (bid < 1024) {                       // W1: 1,048,576 f32 = 262,144 f32x4
        int idx = bid * 256 + t;
        f32x4 v = ((const f32x4*)W1)[idx];
        short4_t o;
        o[0] = (short)f2bf(v[0]); o[1] = (short)f2bf(v[1]);
        o[2] = (short)f2bf(v[2]); o[3] = (short)f2bf(v[3]);
        ((short4_t*)w1b)[idx] = o;
    } else {                                // one block per packed row p
        int p = bid - 1024;                 // 0..2175
        if (p < NTRI) {
            int i, j; tri_unpack(p, i, j);
            w2p[p * 256 + t] = f2bf(W2[(i * 64 + j) * 256L + t]);
            if (t == 0) b2p[p] = b2[i * 64 + j];
        } else {
            w2p[p * 256 + t] = 0;
            if (t == 0) b2p[p] = 0.f;
        }
    }
}

// --------- GEMM1: BM=64, BN=256(full), split-K=8; f32 A cast in staging; bf16 partials
// P[kz][8192,256] = metric[8192, kz*512:+512] @ W1bf[256, same]^T   (round-4 proven)
__global__ __launch_bounds__(256, 2) void gemm1_k(const float* __restrict__ A,
                                                  const unsigned short* __restrict__ B,
                                                  unsigned short* __restrict__ P) {
    __shared__ unsigned short As[64 * 64];    // 8 KB
    __shared__ unsigned short Bs[256 * 64];   // 32 KB
    const int tid  = threadIdx.x;
    const int lane = tid & 63;
    const int w    = tid >> 6;
    const int wm   = w >> 1, wn = w & 1;      // wave tile: 32 rows x 128 cols
    const long bm  = (long)blockIdx.x * 64;
    const int  kz  = blockIdx.y;

    f32x4 acc[2][8];
#pragma unroll
    for (int m = 0; m < 2; m++)
#pragma unroll
        for (int n = 0; n < 8; n++) acc[m][n] = (f32x4){0.f, 0.f, 0.f, 0.f};

    const int rB = tid >> 3;         // 0..31
    const int cB = (tid & 7) * 8;    // bf16 col

    for (int kk = kz * 512; kk < kz * 512 + 512; kk += 64) {
#pragma unroll
        for (int i = 0; i < 8; i++)
            gload_lds16(B + (i * 32 + rB) * 4096L + kk + cB,
                        (char*)Bs + i * 4096 + tid * 16);
#pragma unroll
        for (int i = 0; i < 2; i++) {
            const int row = i * 32 + rB;
            const float* src = A + (bm + row) * 4096L + kk + cB;
            f32x4 a0 = ((const f32x4*)src)[0];
            f32x4 a1 = ((const f32x4*)src)[1];
            short8 ob;
#pragma unroll
            for (int e = 0; e < 4; e++) ob[e]     = (short)f2bf_hw(a0[e]);
#pragma unroll
            for (int e = 0; e < 4; e++) ob[4 + e] = (short)f2bf_hw(a1[e]);
            *(short8*)&As[row * 64 + cB] = ob;
        }
        __syncthreads();

#pragma unroll
        for (int kq = 0; kq < 2; kq++) {
            short8 af0 = *(const short8*)&As[(wm * 32 + 0 * 16 + (lane & 15)) * 64 +
                                             kq * 32 + (lane >> 4) * 8];
            short8 af1 = *(const short8*)&As[(wm * 32 + 1 * 16 + (lane & 15)) * 64 +
                                             kq * 32 + (lane >> 4) * 8];
#pragma unroll
            for (int n = 0; n < 8; n++) {
                short8 bfn = *(const short8*)&Bs[(wn * 128 + n * 16 + (lane & 15)) * 64 +
                                                 kq * 32 + (lane >> 4) * 8];
                acc[0][n] = __builtin_amdgcn_mfma_f32_16x16x32_bf16(af0, bfn, acc[0][n], 0, 0, 0);
                acc[1][n] = __builtin_amdgcn_mfma_f32_16x16x32_bf16(af1, bfn, acc[1][n], 0, 0, 0);
            }
        }
        __syncthreads();
    }

    unsigned short* Pk = P + (long)kz * (8192L * 256);
#pragma unroll
    for (int n = 0; n < 8; n++) {
        long col = wn * 128 + n * 16 + (lane & 15);
#pragma unroll
        for (int m = 0; m < 2; m++)
#pragma unroll
            for (int r = 0; r < 4; r++) {
                long row = bm + wm * 32 + m * 16 + (lane >> 4) * 4 + r;
                Pk[row * 256 + col] = f2bf(acc[m][n][r]);
            }
    }
}

// --------------------------------- reduce 8 bf16 partials + b1 + tanh -> h (bf16)
__global__ __launch_bounds__(256) void reduce_h_k(const unsigned short* __restrict__ P,
                                                  const float* __restrict__ b1,
                                                  unsigned short* __restrict__ h) {
    const int idx = blockIdx.x * 256 + threadIdx.x;   // 262,144 short8 groups
    float s[8];
#pragma unroll
    for (int e = 0; e < 8; e++) s[e] = 0.f;
#pragma unroll
    for (int kz = 0; kz < SPLITK; kz++) {
        short8 v = ((const short8*)(P + (long)kz * 2097152))[idx];
#pragma unroll
        for (int e = 0; e < 8; e++) s[e] += bf2f((unsigned short)v[e]);
    }
    const int cb = (idx & 31) * 8;
    f32x4 bv0 = *(const f32x4*)(b1 + cb);
    f32x4 bv1 = *(const f32x4*)(b1 + cb + 4);
    short8 o;
#pragma unroll
    for (int e = 0; e < 4; e++) o[e]     = (short)f2bf(tanhf(s[e] + bv0[e]));
#pragma unroll
    for (int e = 0; e < 4; e++) o[4 + e] = (short)f2bf(tanhf(s[4 + e] + bv1[e]));
    ((short8*)h)[idx] = o;
}

// ------------------- GEMM2 packed: mlpP[8192,2176] = h @ W2p^T + b2p -> bf16
// BM=128, BN=128, BK=64 (round-4 proven)
__global__ __launch_bounds__(256, 2) void gemm2p_k(const unsigned short* __restrict__ A,
                                                   const unsigned short* __restrict__ B,
                                                   const float* __restrict__ bias,
                                                   unsigned short* __restrict__ C) {
    __shared__ unsigned short As[128 * 64];
    __shared__ unsigned short Bs[128 * 64];
    const int tid  = threadIdx.x;
    const int lane = tid & 63;
    const int w    = tid >> 6;
    const int wm   = w >> 1, wn = w & 1;
    const long bm  = (long)blockIdx.x * 128;
    const long bn  = (long)blockIdx.y * 128;   // < 2176

    f32x4 acc[4][4];
#pragma unroll
    for (int m = 0; m < 4; m++)
#pragma unroll
        for (int n = 0; n < 4; n++) acc[m][n] = (f32x4){0.f, 0.f, 0.f, 0.f};

    const int r0 = tid >> 3;
    const int c0 = (tid & 7) * 8;

    for (int kk = 0; kk < 256; kk += 64) {
#pragma unroll
        for (int i = 0; i < 4; i++) {
            gload_lds16(A + (bm + i * 32 + r0) * 256L + kk + c0,
                        (char*)As + i * 4096 + tid * 16);
            gload_lds16(B + (bn + i * 32 + r0) * 256L + kk + c0,
                        (char*)Bs + i * 4096 + tid * 16);
        }
        __syncthreads();

        short8 af[4][2], bf[4][2];
#pragma unroll
        for (int m = 0; m < 4; m++)
#pragma unroll
            for (int kq = 0; kq < 2; kq++)
                af[m][kq] = *(const short8*)&As[(wm * 64 + m * 16 + (lane & 15)) * 64 +
                                                kq * 32 + (lane >> 4) * 8];
#pragma unroll
        for (int n = 0; n < 4; n++)
#pragma unroll
            for (int kq = 0; kq < 2; kq++)
                bf[n][kq] = *(const short8*)&Bs[(wn * 64 + n * 16 + (lane & 15)) * 64 +
                                                kq * 32 + (lane >> 4) * 8];
#pragma unroll
        for (int m = 0; m < 4; m++)
#pragma unroll
            for (int n = 0; n < 4; n++) {
                acc[m][n] = __builtin_amdgcn_mfma_f32_16x16x32_bf16(af[m][0], bf[n][0],
                                                                    acc[m][n], 0, 0, 0);
                acc[m][n] = __builtin_amdgcn_mfma_f32_16x16x32_bf16(af[m][1], bf[n][1],
                                                                    acc[m][n], 0, 0, 0);
            }
        __syncthreads();
    }

#pragma unroll
    for (int n = 0; n < 4; n++) {
        long col = bn + wn * 64 + n * 16 + (lane & 15);
        float bv = bias[col];
#pragma unroll
        for (int m = 0; m < 4; m++)
#pragma unroll
            for (int r = 0; r < 4; r++) {
                long row = bm + wm * 64 + m * 16 + (lane >> 4) * 4 + r;
                C[row * NPACK + col] = f2bf(acc[m][n][r] + bv);
            }
    }
}

// ---- finalize: scatter packed mlp -> tri LDS; norms -> adt; out = metric + adt*F_sym
// Round-4 proven, plus nontemporal final store (out is write-once, never re-read:
// keep it out of L2/L3 so the concurrent metric/ricci/mlpP reads stay cached).
__global__ __launch_bounds__(256) void finalize3_k(const float* __restrict__ metric,
                                                   const float* __restrict__ ricci,
                                                   const unsigned short* __restrict__ mlpP,
                                                   float* __restrict__ out) {
    const int b = blockIdx.x;
    const int t = threadIdx.x;
    const long mbase = (long)b * 4096;
    const long pbase = (long)b * NPACK;
    __shared__ float s_f[64 * 65];  // lower-tri values live at [i*65 + j], j<=i
    __shared__ float red[8];
    __shared__ float s_adt;

    // phase 1: scatter packed mlp (bf16) into s_f
    const short8* mp8 = (const short8*)(mlpP + pbase);
    {
        short8 v = mp8[t];                       // p = t*8 .. t*8+7  (< 2048)
#pragma unroll
        for (int e = 0; e < 8; e++) {
            int p = t * 8 + e, i, j;
            tri_unpack(p, i, j);
            s_f[i * 65 + j] = bf2f((unsigned short)v[e]);
        }
        if (t < 4) {                             // p = 2048 .. 2079
            short8 v2 = mp8[256 + t];
#pragma unroll
            for (int e = 0; e < 8; e++) {
                int p = 2048 + t * 8 + e, i, j;
                tri_unpack(p, i, j);
                s_f[i * 65 + j] = bf2f((unsigned short)v2[e]);
            }
        }
    }
    __syncthreads();

    // phase 2: norms + fold -2*ricci into lower-tri slots (unique owner per slot)
    const f32x4* met4 = (const f32x4*)(metric + mbase);
    const f32x4* ric4 = (const f32x4*)(ricci + mbase);
    f32x4 mm[4];
    float msq = 0.f, rsq = 0.f;
#pragma unroll
    for (int k = 0; k < 4; k++) {
        int v = k * 256 + t;
        f32x4 r = ric4[v];
        f32x4 m = met4[v];
        mm[k] = m;
        msq += m[0]*m[0] + m[1]*m[1] + m[2]*m[2] + m[3]*m[3];
        rsq += r[0]*r[0] + r[1]*r[1] + r[2]*r[2] + r[3]*r[3];
        int e0 = v * 4;
        int i = e0 >> 6, j0 = e0 & 63;
#pragma unroll
        for (int e = 0; e < 4; e++) {
            int j = j0 + e;
            if (j <= i) s_f[i * 65 + j] -= 2.f * r[e];
        }
    }
#pragma unroll
    for (int off = 32; off > 0; off >>= 1) {
        msq += __shfl_down(msq, off);
        rsq += __shfl_down(rsq, off);
    }
    if ((t & 63) == 0) { red[t >> 6] = msq; red[4 + (t >> 6)] = rsq; }
    __syncthreads();
    if (t == 0) {
        float tm = red[0] + red[1] + red[2] + red[3];
        float tr = red[4] + red[5] + red[6] + red[7];
        s_adt = DTC * fminf(1.0f, 0.1f * sqrtf(tm) / (sqrtf(tr) + EPSF));
    }
    __syncthreads();

    // phase 3: out = metric + adt * F[max][min]  (nontemporal store)
    const float adt = s_adt;
    f32x4* out4 = (f32x4*)(out + mbase);
#pragma unroll
    for (int k = 0; k < 4; k++) {
        int v = k * 256 + t;
        int e0 = v * 4;
        int i = e0 >> 6, j0 = e0 & 63;
        f32x4 o;
#pragma unroll
        for (int e = 0; e < 4; e++) {
            int j = j0 + e;
            int mx = i > j ? i : j;
            int mn = i > j ? j : i;
            o[e] = mm[k][e] + adt * s_f[mx * 65 + mn];
        }
        __builtin_nontemporal_store(o, &out4[v]);
    }
}

// ---------------------------------------------------------------------- launcher
extern "C" void kernel_launch(void* const* d_in, const int* in_sizes, int n_in,
                              void* d_out, int out_size, void* d_ws, size_t ws_size,
                              hipStream_t stream) {
    const float* metric = (const float*)d_in[0];  // [8192,64,64]
    const float* ricci  = (const float*)d_in[1];  // [8192,64,64]
    const float* W1     = (const float*)d_in[2];  // [256,4096]
    const float* b1     = (const float*)d_in[3];  // [256]
    const float* W2     = (const float*)d_in[4];  // [4096,256]
    const float* b2     = (const float*)d_in[5];  // [4096]
    float* out = (float*)d_out;

    const int B = 8192;

    char* ws = (char*)d_ws;
    unsigned short* mlpP = (unsigned short*)(ws);                // 8192*2176*2 = 35,651,584
    unsigned short* w1b  = (unsigned short*)(ws + 35651584);     // 2,097,152
    unsigned short* w2p  = (unsigned short*)(ws + 37748736);     // 2176*256*2 = 1,114,112
    float*          b2p  = (float*)(ws + 38862848);              // 2176*4     = 8,704
    unsigned short* hbf  = (unsigned short*)(ws + 38871552);     // 8192*256*2 = 4,194,304
    // split-K bf16 partials live in d_out (dead until finalize): 8*8192*256*2 = 33.5 MB
    unsigned short* part = (unsigned short*)out;

    // pack/cast weights (W1 cast: blocks 0..1023; W2/b2 tri-pack: blocks 1024..3199)
    pack_k<<<dim3(1024 + NPACK), dim3(256), 0, stream>>>(W1, W2, b2, w1b, w2p, b2p);

    // GEMM1: BM=64 x BN=256(full) x split-K=8 -> bf16 partials in d_out (4 blocks/CU)
    gemm1_k<<<dim3(B / 64, SPLITK), dim3(256), 0, stream>>>(metric, w1b, part);
    // h = tanh(sum partials + b1) -> bf16
    reduce_h_k<<<dim3(B * 256 / 8 / 256), dim3(256), 0, stream>>>(part, b1, hbf);
    // mlpP = h @ W2p^T + b2p -> bf16 packed lower-tri columns
    gemm2p_k<<<dim3(B / 128, NPACK / 128), dim3(256), 0, stream>>>(hbf, w2p, b2p, mlpP);
    // out = metric + adt * sym_lower(-2*ricci + mlp)
    finalize3_k<<<dim3(B), dim3(256), 0, stream>>>(metric, ricci, mlpP, out);

    (void)in_sizes; (void)n_in; (void)out_size; (void)ws_size;
}